// Round 3
// baseline (231.430 us; speedup 1.0000x reference)
//
#include <hip/hip_runtime.h>

#define NDIM 4096
#define B_LG 256
#define B_SM 256
#define R_LG 64
#define R_SM 16
#define BLOCK 1024

// One 1024-thread block (16 waves) computes one batch's GEMV:
//   y[r] = sum_d x[d] * A[d][r],  A is [D][R] row-major (r contiguous).
// All tensors are float32 (harness upcasts the reference's fp16).
// Each thread loads one float4 (4 consecutive r) per iter; the block reads a
// contiguous 16KB chunk of A per iter. fp32 accumulate; shuffle-tree within
// wave, LDS across the 16 waves.
template<int R>
__device__ __forceinline__ void lora_gemv_block(
    const float* __restrict__ xb,   // [NDIM]
    const float* __restrict__ Ab,   // [NDIM][R]
    float* __restrict__ yb)         // [R]
{
    constexpr int WAVES = BLOCK / 64;     // 16
    constexpr int VEC   = 4;              // floats per 16B load
    constexpr int LPR   = R / VEC;        // lanes per A-row: 16 (R=64) or 4 (R=16)
    constexpr int ROWS  = BLOCK / LPR;    // A-rows per block-iter: 64 or 256
    constexpr int ITERS = NDIM / ROWS;    // 64 or 16

    __shared__ float xs[NDIM];            // 16 KB
    __shared__ float red[WAVES][LPR][VEC];

    const int t = threadIdx.x;

    // Stage x row into LDS: exactly one float4 per thread (NDIM/4 == BLOCK).
    {
        const float4* src = reinterpret_cast<const float4*>(xb);
        float4* dst = reinterpret_cast<float4*>(xs);
        dst[t] = src[t];
    }
    __syncthreads();

    const int d_sub  = t / LPR;          // A-row within the iter chunk
    const int r_base = (t % LPR) * VEC;  // 4-column slice

    float acc[VEC];
#pragma unroll
    for (int j = 0; j < VEC; ++j) acc[j] = 0.0f;

#pragma unroll 4
    for (int i = 0; i < ITERS; ++i) {
        const int d = i * ROWS + d_sub;
        const float4 av = *reinterpret_cast<const float4*>(Ab + (size_t)d * R + r_base);
        const float xv = xs[d];
        acc[0] = fmaf(xv, av.x, acc[0]);
        acc[1] = fmaf(xv, av.y, acc[1]);
        acc[2] = fmaf(xv, av.z, acc[2]);
        acc[3] = fmaf(xv, av.w, acc[3]);
    }

    // Wave-level tree reduction: lanes with equal (lane % LPR) share an
    // r-slice (64 % LPR == 0 so t % LPR == lane % LPR).
#pragma unroll
    for (int off = 32; off >= LPR; off >>= 1) {
#pragma unroll
        for (int j = 0; j < VEC; ++j)
            acc[j] += __shfl_down(acc[j], off, 64);
    }

    const int wave = t >> 6;
    const int lane = t & 63;
    if (lane < LPR) {
#pragma unroll
        for (int j = 0; j < VEC; ++j) red[wave][lane][j] = acc[j];
    }
    __syncthreads();

    // Cross-wave finish: thread r sums the WAVES partials.
    if (t < R) {
        const int rl = t / VEC, j = t % VEC;
        float v = 0.0f;
#pragma unroll
        for (int w = 0; w < WAVES; ++w) v += red[w][rl][j];
        yb[t] = v;
    }
}

__global__ __launch_bounds__(BLOCK, 8)
void SequentialLoraA_kernel(const float* __restrict__ x,
                            const int* __restrict__ wids_l,
                            const int* __restrict__ wids_s,
                            const float* __restrict__ Al,
                            const float* __restrict__ As,
                            float* __restrict__ out)
{
    // Interleave: even blocks -> large batches, odd blocks -> small batches,
    // so each CU (2 blocks resident) gets one of each and there is no
    // large-only tail.
    const int pair  = blockIdx.x >> 1;
    const bool big  = (blockIdx.x & 1) == 0;
    if (big) {
        const int wid = wids_l[pair];
        lora_gemv_block<R_LG>(x + (size_t)pair * NDIM,
                              Al + (size_t)wid * NDIM * R_LG,
                              out + (size_t)pair * R_LG);
    } else {
        const int wid = wids_s[pair];
        lora_gemv_block<R_SM>(x + (size_t)(B_LG + pair) * NDIM,
                              As + (size_t)wid * NDIM * R_SM,
                              out + (size_t)B_LG * R_LG + (size_t)pair * R_SM);
    }
}

extern "C" void kernel_launch(void* const* d_in, const int* in_sizes, int n_in,
                              void* d_out, int out_size, void* d_ws, size_t ws_size,
                              hipStream_t stream) {
    const float* x      = (const float*)d_in[0];
    const int*   wids_l = (const int*)d_in[1];
    const int*   wids_s = (const int*)d_in[2];
    const float* Al     = (const float*)d_in[3];
    const float* As     = (const float*)d_in[4];
    float* out = (float*)d_out;

    SequentialLoraA_kernel<<<B_LG + B_SM, BLOCK, 0, stream>>>(x, wids_l, wids_s, Al, As, out);
}